// Round 1
// baseline (1167.753 us; speedup 1.0000x reference)
//
#include <hip/hip_runtime.h>

// ---------------------------------------------------------------------------
// GCN graph classifier:
//   h1 = relu(gcnconv(x, W1, b1));  h2 = relu(gcnconv(h1, W2, b2));
//   g  = mean_pool(h2, batch);      out = g @ Wl + bl
// gcnconv: xw = x@W; deg[c] = indeg + 1 (self loop); dis = rsqrt(deg);
//          agg[c] += dis[r]*dis[c]*xw[r] over edges; += dis[i]^2*xw[i] (self);
//          out = agg + b
// ---------------------------------------------------------------------------

// ---- degree ----------------------------------------------------------------
__global__ __launch_bounds__(256) void deg_kernel(const int* __restrict__ col,
                                                  float* __restrict__ deg, int E) {
    int e = blockIdx.x * 256 + threadIdx.x;
    if (e < E) atomicAdd(&deg[col[e]], 1.0f);
}

__global__ __launch_bounds__(256) void dis_kernel(float* __restrict__ deg, int n) {
    int i = blockIdx.x * 256 + threadIdx.x;
    if (i < n) deg[i] = rsqrtf(deg[i] + 1.0f);   // +1 = self loop
}

// ---- per-node GEMM: out[n][64] = x[n][INC] @ W[INC][64] --------------------
template <int INC>
__global__ __launch_bounds__(256) void gemm_node(const float* __restrict__ x,
                                                 const float* __restrict__ W,
                                                 float* __restrict__ out, int n) {
    __shared__ float Wl[INC * 64];
    __shared__ float xr[4][INC];
    for (int i = threadIdx.x; i < INC * 64; i += 256) Wl[i] = W[i];
    const int wid = threadIdx.x >> 6, lane = threadIdx.x & 63;
    for (int base = blockIdx.x * 4; base < n; base += gridDim.x * 4) {
        const int node = base + wid;
        __syncthreads();                 // protect xr reuse across iterations
        if (node < n) {
            for (int k = lane; k < INC; k += 64)
                xr[wid][k] = x[(long)node * INC + k];
        }
        __syncthreads();
        if (node < n) {
            float acc = 0.0f;
#pragma unroll
            for (int k = 0; k < INC; ++k)
                acc = fmaf(xr[wid][k], Wl[k * 64 + lane], acc);
            out[(long)node * 64 + lane] = acc;
        }
    }
}

// ---- edge scatter: agg[col][l] += dis[row]*dis[col]*xw[row][l] -------------
__global__ __launch_bounds__(256) void scatter_kernel(const float* __restrict__ xw,
                                                      const int* __restrict__ row,
                                                      const int* __restrict__ col,
                                                      const float* __restrict__ dis,
                                                      float* __restrict__ agg, int E) {
    long gid = (long)blockIdx.x * 256 + threadIdx.x;
    if (gid >= (long)E * 64) return;
    int e = (int)(gid >> 6);
    int l = (int)(gid & 63);
    int r = row[e], c = col[e];
    float nrm = dis[r] * dis[c];
    atomicAdd(&agg[c * 64 + l], nrm * xw[r * 64 + l]);
}

// ---- self-loop + bias + relu (in place on agg) -----------------------------
__global__ __launch_bounds__(256) void bias_relu_kernel(float* __restrict__ agg,
                                                        const float* __restrict__ xw,
                                                        const float* __restrict__ dis,
                                                        const float* __restrict__ b,
                                                        int n) {
    int gid = blockIdx.x * 256 + threadIdx.x;
    if (gid >= n * 64) return;
    int i = gid >> 6, l = gid & 63;
    float d = dis[i];
    float v = agg[gid] + d * d * xw[gid] + b[l];
    agg[gid] = fmaxf(v, 0.0f);
}

// ---- segmented mean-pool (batch sorted): one wave per 512-node chunk -------
__global__ __launch_bounds__(64) void pool_kernel(const float* __restrict__ h,
                                                  const int* __restrict__ batch,
                                                  float* __restrict__ pool,
                                                  float* __restrict__ cnt, int n) {
    const int lane = threadIdx.x;
    const int start = blockIdx.x * 512;
    const int end = min(start + 512, n);
    if (start >= end) return;
    int gcur = batch[start];
    float acc = 0.0f;
    int c = 0;
    for (int i = start; i < end; ++i) {
        int g = batch[i];           // wave-uniform
        if (g != gcur) {
            atomicAdd(&pool[gcur * 64 + lane], acc);
            if (lane == 0) atomicAdd(&cnt[gcur], (float)c);
            acc = 0.0f; c = 0; gcur = g;
        }
        acc += h[(long)i * 64 + lane];
        ++c;
    }
    atomicAdd(&pool[gcur * 64 + lane], acc);
    if (lane == 0) atomicAdd(&cnt[gcur], (float)c);
}

// ---- final: out[64][10] = (pool/cnt) @ Wl + bl -----------------------------
__global__ __launch_bounds__(640) void final_kernel(const float* __restrict__ pool,
                                                    const float* __restrict__ cnt,
                                                    const float* __restrict__ Wl,
                                                    const float* __restrict__ bl,
                                                    float* __restrict__ out) {
    int tid = threadIdx.x;            // 640 = 64 graphs * 10 outputs
    int g = tid / 10, o = tid % 10;
    float inv = 1.0f / fmaxf(cnt[g], 1.0f);
    float acc = 0.0f;
#pragma unroll
    for (int l = 0; l < 64; ++l)
        acc = fmaf(pool[g * 64 + l] * inv, Wl[l * 10 + o], acc);
    out[tid] = acc + bl[o];
}

extern "C" void kernel_launch(void* const* d_in, const int* in_sizes, int n_in,
                              void* d_out, int out_size, void* d_ws, size_t ws_size,
                              hipStream_t stream) {
    const float* x  = (const float*)d_in[0];
    const float* W1 = (const float*)d_in[1];
    const float* b1 = (const float*)d_in[2];
    const float* W2 = (const float*)d_in[3];
    const float* b2 = (const float*)d_in[4];
    const float* Wl = (const float*)d_in[5];
    const float* bl = (const float*)d_in[6];
    const int*   ei = (const int*)d_in[7];    // [2, E] -> row = ei, col = ei + E
    const int*   batch = (const int*)d_in[8];
    float* out = (float*)d_out;

    const int n = in_sizes[8];           // 100000 nodes
    const int E = in_sizes[7] / 2;       // 1600000 edges
    const int F = 64;                    // hidden width

    const int* row = ei;
    const int* col = ei + E;

    // workspace layout (f32)
    float* dis = (float*)d_ws;                 // [n]     (deg first, then rsqrt)
    float* A   = dis + n;                      // [n*64]  xw buffer
    float* B   = A + (size_t)n * F;            // [n*64]  agg / h buffer
    float* pool = B + (size_t)n * F;           // [64*64]
    float* cnt  = pool + 64 * 64;              // [64]

    const int nb_edge   = (E + 255) / 256;
    const int nb_node   = (n + 255) / 256;
    const long scatter_total = (long)E * F;
    const int nb_scatter = (int)((scatter_total + 255) / 256);
    const int nb_feat   = (n * F + 255) / 256;
    const int nb_pool   = (n + 511) / 512;

    // degree -> dis
    hipMemsetAsync(dis, 0, (size_t)n * sizeof(float), stream);
    deg_kernel<<<nb_edge, 256, 0, stream>>>(col, dis, E);
    dis_kernel<<<nb_node, 256, 0, stream>>>(dis, n);

    // ---- layer 1 ----
    gemm_node<128><<<1024, 256, 0, stream>>>(x, W1, A, n);
    hipMemsetAsync(B, 0, (size_t)n * F * sizeof(float), stream);
    scatter_kernel<<<nb_scatter, 256, 0, stream>>>(A, row, col, dis, B, E);
    bias_relu_kernel<<<nb_feat, 256, 0, stream>>>(B, A, dis, b1, n);   // B = h1

    // ---- layer 2 ----
    gemm_node<64><<<1024, 256, 0, stream>>>(B, W2, A, n);              // A = xw2
    hipMemsetAsync(B, 0, (size_t)n * F * sizeof(float), stream);
    scatter_kernel<<<nb_scatter, 256, 0, stream>>>(A, row, col, dis, B, E);
    bias_relu_kernel<<<nb_feat, 256, 0, stream>>>(B, A, dis, b2, n);   // B = h2

    // ---- pool + classifier ----
    hipMemsetAsync(pool, 0, (64 * 64 + 64) * sizeof(float), stream);
    pool_kernel<<<nb_pool, 64, 0, stream>>>(B, batch, pool, cnt, n);
    final_kernel<<<1, 640, 0, stream>>>(pool, cnt, Wl, bl, out);
}

// Round 2
// 655.064 us; speedup vs baseline: 1.7827x; 1.7827x over previous
//
#include <hip/hip_runtime.h>

// ---------------------------------------------------------------------------
// GCN graph classifier — pull-based (CSR) aggregation, built once, used twice.
//   h1 = relu(gcnconv(x, W1, b1));  h2 = relu(gcnconv(h1, W2, b2));
//   g  = mean_pool(h2, batch);      out = g @ Wl + bl
// ---------------------------------------------------------------------------

// ---- degree histogram (int) ------------------------------------------------
__global__ __launch_bounds__(256) void deg_kernel(const int* __restrict__ col,
                                                  int* __restrict__ deg, int E) {
    int e = blockIdx.x * 256 + threadIdx.x;
    if (e < E) atomicAdd(&deg[col[e]], 1);
}

// ---- dis[i] = rsqrt(deg+1) -------------------------------------------------
__global__ __launch_bounds__(256) void dis_kernel(const int* __restrict__ deg,
                                                  float* __restrict__ dis, int n) {
    int i = blockIdx.x * 256 + threadIdx.x;
    if (i < n) dis[i] = rsqrtf((float)deg[i] + 1.0f);
}

// ---- scan step 1: per-block sums (512 elems/block) -------------------------
__global__ __launch_bounds__(512) void block_sum_kernel(const int* __restrict__ deg,
                                                        int* __restrict__ bsums, int n) {
    __shared__ int sm[512];
    int i = blockIdx.x * 512 + threadIdx.x;
    sm[threadIdx.x] = (i < n) ? deg[i] : 0;
    __syncthreads();
    for (int s = 256; s > 0; s >>= 1) {
        if (threadIdx.x < s) sm[threadIdx.x] += sm[threadIdx.x + s];
        __syncthreads();
    }
    if (threadIdx.x == 0) bsums[blockIdx.x] = sm[0];
}

// ---- scan step 2: exclusive scan of block sums (nb <= 256, one block) ------
__global__ __launch_bounds__(256) void scan_bsums_kernel(int* __restrict__ bsums, int nb) {
    __shared__ int sm[256];
    int v = (threadIdx.x < nb) ? bsums[threadIdx.x] : 0;
    sm[threadIdx.x] = v;
    __syncthreads();
    for (int off = 1; off < 256; off <<= 1) {
        int t = (threadIdx.x >= off) ? sm[threadIdx.x - off] : 0;
        __syncthreads();
        sm[threadIdx.x] += t;
        __syncthreads();
    }
    if (threadIdx.x < nb) bsums[threadIdx.x] = sm[threadIdx.x] - v;  // exclusive
}

// ---- scan step 3: local exclusive scan + block offset -> row_ptr -----------
__global__ __launch_bounds__(512) void scan_write_kernel(const int* __restrict__ deg,
                                                         const int* __restrict__ bsums,
                                                         int* __restrict__ rowptr,
                                                         int n, int E) {
    __shared__ int sm[512];
    int i = blockIdx.x * 512 + threadIdx.x;
    int v = (i < n) ? deg[i] : 0;
    sm[threadIdx.x] = v;
    __syncthreads();
    for (int off = 1; off < 512; off <<= 1) {
        int t = (threadIdx.x >= off) ? sm[threadIdx.x - off] : 0;
        __syncthreads();
        sm[threadIdx.x] += t;
        __syncthreads();
    }
    if (i < n) rowptr[i] = bsums[blockIdx.x] + sm[threadIdx.x] - v;  // exclusive
    if (blockIdx.x == 0 && threadIdx.x == 0) rowptr[n] = E;
}

// ---- CSR fill: csr[pos] = (src, norm) --------------------------------------
__global__ __launch_bounds__(256) void fill_csr_kernel(const int* __restrict__ row,
                                                       const int* __restrict__ col,
                                                       const float* __restrict__ dis,
                                                       const int* __restrict__ rowptr,
                                                       int* __restrict__ fill,
                                                       int2* __restrict__ csr, int E) {
    int e = blockIdx.x * 256 + threadIdx.x;
    if (e >= E) return;
    int r = row[e], c = col[e];
    int pos = rowptr[c] + atomicAdd(&fill[c], 1);
    csr[pos] = make_int2(r, __float_as_int(dis[r] * dis[c]));
}

// ---- per-node GEMM: out[n][64] = x[n][INC] @ W[INC][64] --------------------
template <int INC>
__global__ __launch_bounds__(256) void gemm_node(const float* __restrict__ x,
                                                 const float* __restrict__ W,
                                                 float* __restrict__ out, int n) {
    __shared__ float Wl[INC * 64];
    __shared__ float xr[4][INC];
    for (int i = threadIdx.x; i < INC * 64; i += 256) Wl[i] = W[i];
    const int wid = threadIdx.x >> 6, lane = threadIdx.x & 63;
    for (int base = blockIdx.x * 4; base < n; base += gridDim.x * 4) {
        const int node = base + wid;
        __syncthreads();                 // protect xr reuse across iterations
        if (node < n) {
            for (int k = lane; k < INC; k += 64)
                xr[wid][k] = x[(size_t)node * INC + k];
        }
        __syncthreads();
        if (node < n) {
            float acc = 0.0f;
#pragma unroll
            for (int k = 0; k < INC; ++k)
                acc = fmaf(xr[wid][k], Wl[k * 64 + lane], acc);
            out[(size_t)node * 64 + lane] = acc;
        }
    }
}

// ---- fused pull-aggregate + self-loop + bias + relu ------------------------
__global__ __launch_bounds__(256) void gcn_pull_kernel(const float* __restrict__ xw,
                                                       const int2* __restrict__ csr,
                                                       const int* __restrict__ rowptr,
                                                       const float* __restrict__ dis,
                                                       const float* __restrict__ b,
                                                       float* __restrict__ out, int n) {
    const int lane = threadIdx.x & 63;
    const int wid = threadIdx.x >> 6;
    const float bl_ = b[lane];
    for (int i = blockIdx.x * 4 + wid; i < n; i += gridDim.x * 4) {
        int s = rowptr[i], t = rowptr[i + 1];
        float di = dis[i];
        float acc = di * di * xw[(size_t)i * 64 + lane];   // self loop
        int e = s;
        for (; e + 1 < t; e += 2) {                         // 2-deep to pipeline gathers
            int2 p0 = csr[e], p1 = csr[e + 1];
            acc = fmaf(__int_as_float(p0.y), xw[(size_t)p0.x * 64 + lane], acc);
            acc = fmaf(__int_as_float(p1.y), xw[(size_t)p1.x * 64 + lane], acc);
        }
        if (e < t) {
            int2 p = csr[e];
            acc = fmaf(__int_as_float(p.y), xw[(size_t)p.x * 64 + lane], acc);
        }
        out[(size_t)i * 64 + lane] = fmaxf(acc + bl_, 0.0f);
    }
}

// ---- segmented mean-pool (batch sorted): wave per 256-node chunk -----------
__global__ __launch_bounds__(256) void pool_kernel(const float* __restrict__ h,
                                                   const int* __restrict__ batch,
                                                   float* __restrict__ pool,
                                                   float* __restrict__ cnt, int n) {
    const int lane = threadIdx.x & 63;
    const int wid = threadIdx.x >> 6;
    const int start = (blockIdx.x * 4 + wid) * 256;
    const int end = min(start + 256, n);
    if (start >= end) return;
    int gcur = batch[start];
    float acc = 0.0f;
    int c = 0;
    for (int i = start; i < end; ++i) {
        int g = batch[i];           // wave-uniform
        if (g != gcur) {
            atomicAdd(&pool[gcur * 64 + lane], acc);
            if (lane == 0) atomicAdd(&cnt[gcur], (float)c);
            acc = 0.0f; c = 0; gcur = g;
        }
        acc += h[(size_t)i * 64 + lane];
        ++c;
    }
    atomicAdd(&pool[gcur * 64 + lane], acc);
    if (lane == 0) atomicAdd(&cnt[gcur], (float)c);
}

// ---- final: out[64][10] = (pool/cnt) @ Wl + bl -----------------------------
__global__ __launch_bounds__(640) void final_kernel(const float* __restrict__ pool,
                                                    const float* __restrict__ cnt,
                                                    const float* __restrict__ Wl,
                                                    const float* __restrict__ bl,
                                                    float* __restrict__ out) {
    int tid = threadIdx.x;            // 640 = 64 graphs * 10 outputs
    int g = tid / 10, o = tid % 10;
    float inv = 1.0f / fmaxf(cnt[g], 1.0f);
    float acc = 0.0f;
#pragma unroll
    for (int l = 0; l < 64; ++l)
        acc = fmaf(pool[g * 64 + l] * inv, Wl[l * 10 + o], acc);
    out[tid] = acc + bl[o];
}

extern "C" void kernel_launch(void* const* d_in, const int* in_sizes, int n_in,
                              void* d_out, int out_size, void* d_ws, size_t ws_size,
                              hipStream_t stream) {
    const float* x  = (const float*)d_in[0];
    const float* W1 = (const float*)d_in[1];
    const float* b1 = (const float*)d_in[2];
    const float* W2 = (const float*)d_in[3];
    const float* b2 = (const float*)d_in[4];
    const float* Wl = (const float*)d_in[5];
    const float* bl = (const float*)d_in[6];
    const int*   ei = (const int*)d_in[7];    // [2, E] -> row = ei, col = ei + E
    const int*   batch = (const int*)d_in[8];
    float* out = (float*)d_out;

    const int n = in_sizes[8];           // 100000 nodes
    const int E = in_sizes[7] / 2;       // 1600000 edges
    const int F = 64;

    const int* row = ei;
    const int* col = ei + E;

    // ---- workspace layout (256B-aligned chunks) ----
    char* p = (char*)d_ws;
    auto alloc = [&](size_t bytes) {
        char* r = p;
        p += (bytes + 255) & ~(size_t)255;
        return r;
    };
    int*   degi   = (int*)  alloc((size_t)n * 4);          // deg, reused as fill
    int*   rowptr = (int*)  alloc((size_t)(n + 1) * 4);
    int*   bsums  = (int*)  alloc(256 * 4);
    float* dis    = (float*)alloc((size_t)n * 4);
    int2*  csr    = (int2*) alloc((size_t)E * 8);
    float* A      = (float*)alloc((size_t)n * F * 4);
    float* B      = (float*)alloc((size_t)n * F * 4);
    float* pool   = (float*)alloc(64 * 64 * 4);
    float* cnt    = (float*)alloc(64 * 4);

    const int nb_edge = (E + 255) / 256;
    const int nb_node = (n + 255) / 256;
    const int nb_scan = (n + 511) / 512;     // 196 for n=100000

    // ---- CSR build (shared by both layers) ----
    hipMemsetAsync(degi, 0, (size_t)n * 4, stream);
    deg_kernel<<<nb_edge, 256, 0, stream>>>(col, degi, E);
    block_sum_kernel<<<nb_scan, 512, 0, stream>>>(degi, bsums, n);
    scan_bsums_kernel<<<1, 256, 0, stream>>>(bsums, nb_scan);
    scan_write_kernel<<<nb_scan, 512, 0, stream>>>(degi, bsums, rowptr, n, E);
    dis_kernel<<<nb_node, 256, 0, stream>>>(degi, dis, n);
    hipMemsetAsync(degi, 0, (size_t)n * 4, stream);        // reuse as fill counters
    fill_csr_kernel<<<nb_edge, 256, 0, stream>>>(row, col, dis, rowptr, degi, csr, E);

    // ---- layer 1 ----
    gemm_node<128><<<1024, 256, 0, stream>>>(x, W1, A, n);
    gcn_pull_kernel<<<2048, 256, 0, stream>>>(A, csr, rowptr, dis, b1, B, n);

    // ---- layer 2 ----
    gemm_node<64><<<1024, 256, 0, stream>>>(B, W2, A, n);
    gcn_pull_kernel<<<2048, 256, 0, stream>>>(A, csr, rowptr, dis, b2, B, n);

    // ---- pool + classifier ----
    hipMemsetAsync(pool, 0, (64 * 64 + 64 + 192) * sizeof(float), stream);
    pool_kernel<<<(n + 1023) / 1024, 256, 0, stream>>>(B, batch, pool, cnt, n);
    final_kernel<<<1, 640, 0, stream>>>(pool, cnt, Wl, bl, out);
}

// Round 3
// 496.928 us; speedup vs baseline: 2.3499x; 1.3182x over previous
//
#include <hip/hip_runtime.h>

// ---------------------------------------------------------------------------
// GCN graph classifier — CSR pull aggregation + bf16 gather tables.
//   h1 = relu(gcnconv(x, W1, b1));  h2 = relu(gcnconv(h1, W2, b2));
//   g  = mean_pool(h2, batch);      out = g @ Wl + bl
// xw tables stored bf16 (halves random-gather traffic); accum always f32.
// ---------------------------------------------------------------------------

static __device__ inline ushort f32_to_bf16_rne(float f) {
    uint32_t u = __float_as_uint(f);
    uint32_t r = (u + 0x7fffu + ((u >> 16) & 1u)) >> 16;
    return (ushort)r;
}

// ---- degree histogram (int) ------------------------------------------------
__global__ __launch_bounds__(256) void deg_kernel(const int* __restrict__ col,
                                                  int* __restrict__ deg, int E) {
    int e = blockIdx.x * 256 + threadIdx.x;
    if (e < E) atomicAdd(&deg[col[e]], 1);
}

// ---- dis[i] = rsqrt(deg+1) -------------------------------------------------
__global__ __launch_bounds__(256) void dis_kernel(const int* __restrict__ deg,
                                                  float* __restrict__ dis, int n) {
    int i = blockIdx.x * 256 + threadIdx.x;
    if (i < n) dis[i] = rsqrtf((float)deg[i] + 1.0f);
}

// ---- scan step 1: per-block sums (512 elems/block) -------------------------
__global__ __launch_bounds__(512) void block_sum_kernel(const int* __restrict__ deg,
                                                        int* __restrict__ bsums, int n) {
    __shared__ int sm[512];
    int i = blockIdx.x * 512 + threadIdx.x;
    sm[threadIdx.x] = (i < n) ? deg[i] : 0;
    __syncthreads();
    for (int s = 256; s > 0; s >>= 1) {
        if (threadIdx.x < s) sm[threadIdx.x] += sm[threadIdx.x + s];
        __syncthreads();
    }
    if (threadIdx.x == 0) bsums[blockIdx.x] = sm[0];
}

// ---- scan step 2: exclusive scan of block sums (nb <= 256, one block) ------
__global__ __launch_bounds__(256) void scan_bsums_kernel(int* __restrict__ bsums, int nb) {
    __shared__ int sm[256];
    int v = (threadIdx.x < nb) ? bsums[threadIdx.x] : 0;
    sm[threadIdx.x] = v;
    __syncthreads();
    for (int off = 1; off < 256; off <<= 1) {
        int t = (threadIdx.x >= off) ? sm[threadIdx.x - off] : 0;
        __syncthreads();
        sm[threadIdx.x] += t;
        __syncthreads();
    }
    if (threadIdx.x < nb) bsums[threadIdx.x] = sm[threadIdx.x] - v;  // exclusive
}

// ---- scan step 3: local exclusive scan + block offset -> row_ptr -----------
__global__ __launch_bounds__(512) void scan_write_kernel(const int* __restrict__ deg,
                                                         const int* __restrict__ bsums,
                                                         int* __restrict__ rowptr,
                                                         int n, int E) {
    __shared__ int sm[512];
    int i = blockIdx.x * 512 + threadIdx.x;
    int v = (i < n) ? deg[i] : 0;
    sm[threadIdx.x] = v;
    __syncthreads();
    for (int off = 1; off < 512; off <<= 1) {
        int t = (threadIdx.x >= off) ? sm[threadIdx.x - off] : 0;
        __syncthreads();
        sm[threadIdx.x] += t;
        __syncthreads();
    }
    if (i < n) rowptr[i] = bsums[blockIdx.x] + sm[threadIdx.x] - v;  // exclusive
    if (blockIdx.x == 0 && threadIdx.x == 0) rowptr[n] = E;
}

// ---- CSR fill: csr[pos] = (src, norm) --------------------------------------
__global__ __launch_bounds__(256) void fill_csr_kernel(const int* __restrict__ row,
                                                       const int* __restrict__ col,
                                                       const float* __restrict__ dis,
                                                       const int* __restrict__ rowptr,
                                                       int* __restrict__ fill,
                                                       int2* __restrict__ csr, int E) {
    int e = blockIdx.x * 256 + threadIdx.x;
    if (e >= E) return;
    int r = row[e], c = col[e];
    int pos = rowptr[c] + atomicAdd(&fill[c], 1);
    csr[pos] = make_int2(r, __float_as_int(dis[r] * dis[c]));
}

// ---- register-tiled GEMM: out_bf16[n][64] = x[n][K] @ W[K][64] -------------
// 64-node x 64-out tile per block (256 thr), 4x4 per thread, K-chunks of 32.
template <int K>
__global__ __launch_bounds__(256) void gemm_tiled(const float* __restrict__ x,
                                                  const float* __restrict__ W,
                                                  ushort* __restrict__ out, int n) {
    __shared__ float As[32][64];     // [k][node]
    __shared__ float Ws[32 * 64];    // [k][out] flat
    const int tid = threadIdx.x;
    const int tr = tid >> 4;         // 0..15 -> node quad
    const int tc = tid & 15;         // 0..15 -> out quad
    const int base = blockIdx.x * 64;

    float acc[4][4];
#pragma unroll
    for (int i = 0; i < 4; ++i)
#pragma unroll
        for (int j = 0; j < 4; ++j) acc[i][j] = 0.0f;

    const int tnode = tid >> 3;          // 0..31
    const int tk4 = (tid & 7) * 4;       // 0,4,...,28

    for (int kc = 0; kc < K; kc += 32) {
        __syncthreads();
        // stage x[base..base+63][kc..kc+31] -> As[k][node]
#pragma unroll
        for (int h = 0; h < 2; ++h) {
            int m = tnode + h * 32;
            int node = base + m;
            float4 v = make_float4(0.f, 0.f, 0.f, 0.f);
            if (node < n) v = *(const float4*)&x[(size_t)node * K + kc + tk4];
            As[tk4 + 0][m] = v.x; As[tk4 + 1][m] = v.y;
            As[tk4 + 2][m] = v.z; As[tk4 + 3][m] = v.w;
        }
        // stage W[kc..kc+31][0..63] (contiguous 2048 floats)
#pragma unroll
        for (int r = 0; r < 2; ++r) {
            int o = tid * 4 + r * 1024;
            *(float4*)&Ws[o] = *(const float4*)&W[kc * 64 + o];
        }
        __syncthreads();
#pragma unroll
        for (int k = 0; k < 32; ++k) {
            float4 a = *(const float4*)&As[k][tr * 4];
            float4 b = *(const float4*)&Ws[k * 64 + tc * 4];
            const float av[4] = {a.x, a.y, a.z, a.w};
            const float bv[4] = {b.x, b.y, b.z, b.w};
#pragma unroll
            for (int i = 0; i < 4; ++i)
#pragma unroll
                for (int j = 0; j < 4; ++j)
                    acc[i][j] = fmaf(av[i], bv[j], acc[i][j]);
        }
    }
    // epilogue: bf16 store
#pragma unroll
    for (int i = 0; i < 4; ++i) {
        int node = base + tr * 4 + i;
        if (node < n) {
            ushort4 st;
            st.x = f32_to_bf16_rne(acc[i][0]);
            st.y = f32_to_bf16_rne(acc[i][1]);
            st.z = f32_to_bf16_rne(acc[i][2]);
            st.w = f32_to_bf16_rne(acc[i][3]);
            *(ushort4*)&out[(size_t)node * 64 + tc * 4] = st;
        }
    }
}

// ---- fused pull-aggregate + self-loop + bias + relu (bf16 gather) ----------
// wave per dst node; half-wave per edge (2 edges in flight); bf162 per lane.
template <int OUT_BF16>
__global__ __launch_bounds__(256) void gcn_pull_kernel(const ushort* __restrict__ xw,
                                                       const int2* __restrict__ csr,
                                                       const int* __restrict__ rowptr,
                                                       const float* __restrict__ dis,
                                                       const float* __restrict__ b,
                                                       void* __restrict__ outv, int n) {
    const int lane = threadIdx.x & 63;
    const int wid = threadIdx.x >> 6;
    const int half = lane >> 5;          // 0/1 -> which edge of the pair
    const int q = lane & 31;             // feature pair index
    const float2 bb = ((const float2*)b)[q];

    for (int i = blockIdx.x * 4 + wid; i < n; i += gridDim.x * 4) {
        int s = rowptr[i], t = rowptr[i + 1];
        float ax = 0.0f, ay = 0.0f;
        if (half == 0) {                 // self loop counted once
            float di = dis[i];
            uint32_t u = *(const uint32_t*)(xw + ((size_t)i << 6) + (q << 1));
            float w = di * di;
            ax = w * __uint_as_float(u << 16);
            ay = w * __uint_as_float(u & 0xffff0000u);
        }
        int e = s + half;
        // 2 edges per half in flight (4 per wave)
        for (; e + 2 < t; e += 4) {
            int2 p0 = csr[e];
            int2 p1 = csr[e + 2];
            uint32_t u0 = *(const uint32_t*)(xw + ((size_t)p0.x << 6) + (q << 1));
            uint32_t u1 = *(const uint32_t*)(xw + ((size_t)p1.x << 6) + (q << 1));
            float n0 = __int_as_float(p0.y), n1 = __int_as_float(p1.y);
            ax = fmaf(n0, __uint_as_float(u0 << 16), ax);
            ay = fmaf(n0, __uint_as_float(u0 & 0xffff0000u), ay);
            ax = fmaf(n1, __uint_as_float(u1 << 16), ax);
            ay = fmaf(n1, __uint_as_float(u1 & 0xffff0000u), ay);
        }
        for (; e < t; e += 2) {
            int2 p = csr[e];
            uint32_t u = *(const uint32_t*)(xw + ((size_t)p.x << 6) + (q << 1));
            float nr = __int_as_float(p.y);
            ax = fmaf(nr, __uint_as_float(u << 16), ax);
            ay = fmaf(nr, __uint_as_float(u & 0xffff0000u), ay);
        }
        // combine the two halves
        ax += __shfl_xor(ax, 32);
        ay += __shfl_xor(ay, 32);
        if (half == 0) {
            float v0 = fmaxf(ax + bb.x, 0.0f);
            float v1 = fmaxf(ay + bb.y, 0.0f);
            if (OUT_BF16) {
                ushort2 st = make_ushort2(f32_to_bf16_rne(v0), f32_to_bf16_rne(v1));
                *(ushort2*)((ushort*)outv + ((size_t)i << 6) + (q << 1)) = st;
            } else {
                *(float2*)((float*)outv + ((size_t)i << 6) + (q << 1)) = make_float2(v0, v1);
            }
        }
    }
}

// ---- segmented mean-pool (batch sorted, bf16 input) ------------------------
__global__ __launch_bounds__(256) void pool_kernel(const ushort* __restrict__ h,
                                                   const int* __restrict__ batch,
                                                   float* __restrict__ pool,
                                                   float* __restrict__ cnt, int n) {
    const int lane = threadIdx.x & 63;
    const int wid = threadIdx.x >> 6;
    const int start = (blockIdx.x * 4 + wid) * 256;
    const int end = min(start + 256, n);
    if (start >= end) return;
    int gcur = batch[start];
    float acc = 0.0f;
    int c = 0;
    for (int i = start; i < end; ++i) {
        int g = batch[i];           // wave-uniform
        if (g != gcur) {
            atomicAdd(&pool[gcur * 64 + lane], acc);
            if (lane == 0) atomicAdd(&cnt[gcur], (float)c);
            acc = 0.0f; c = 0; gcur = g;
        }
        acc += __uint_as_float((uint32_t)h[(size_t)i * 64 + lane] << 16);
        ++c;
    }
    atomicAdd(&pool[gcur * 64 + lane], acc);
    if (lane == 0) atomicAdd(&cnt[gcur], (float)c);
}

// ---- final: out[64][10] = (pool/cnt) @ Wl + bl -----------------------------
__global__ __launch_bounds__(640) void final_kernel(const float* __restrict__ pool,
                                                    const float* __restrict__ cnt,
                                                    const float* __restrict__ Wl,
                                                    const float* __restrict__ bl,
                                                    float* __restrict__ out) {
    int tid = threadIdx.x;            // 640 = 64 graphs * 10 outputs
    int g = tid / 10, o = tid % 10;
    float inv = 1.0f / fmaxf(cnt[g], 1.0f);
    float acc = 0.0f;
#pragma unroll
    for (int l = 0; l < 64; ++l)
        acc = fmaf(pool[g * 64 + l] * inv, Wl[l * 10 + o], acc);
    out[tid] = acc + bl[o];
}

extern "C" void kernel_launch(void* const* d_in, const int* in_sizes, int n_in,
                              void* d_out, int out_size, void* d_ws, size_t ws_size,
                              hipStream_t stream) {
    const float* x  = (const float*)d_in[0];
    const float* W1 = (const float*)d_in[1];
    const float* b1 = (const float*)d_in[2];
    const float* W2 = (const float*)d_in[3];
    const float* b2 = (const float*)d_in[4];
    const float* Wl = (const float*)d_in[5];
    const float* bl = (const float*)d_in[6];
    const int*   ei = (const int*)d_in[7];    // [2, E] -> row = ei, col = ei + E
    const int*   batch = (const int*)d_in[8];
    float* out = (float*)d_out;

    const int n = in_sizes[8];           // 100000 nodes
    const int E = in_sizes[7] / 2;       // 1600000 edges
    const int F = 64;

    const int* row = ei;
    const int* col = ei + E;

    // ---- workspace layout (256B-aligned chunks) ----
    char* p = (char*)d_ws;
    auto alloc = [&](size_t bytes) {
        char* r = p;
        p += (bytes + 255) & ~(size_t)255;
        return r;
    };
    int*    degi   = (int*)   alloc((size_t)n * 4);          // deg, reused as fill
    int*    rowptr = (int*)   alloc((size_t)(n + 1) * 4);
    int*    bsums  = (int*)   alloc(256 * 4);
    float*  dis    = (float*) alloc((size_t)n * 4);
    int2*   csr    = (int2*)  alloc((size_t)E * 8);
    ushort* xwB    = (ushort*)alloc((size_t)n * F * 2);      // bf16 gather table
    float*  B      = (float*) alloc((size_t)n * F * 4);      // h1 f32 / h2 bf16 reuse
    float*  pool   = (float*) alloc(64 * 64 * 4);
    float*  cnt    = (float*) alloc(64 * 4);

    const int nb_edge = (E + 255) / 256;
    const int nb_node = (n + 255) / 256;
    const int nb_scan = (n + 511) / 512;     // 196 for n=100000
    const int nb_gemm = (n + 63) / 64;

    // ---- CSR build (shared by both layers) ----
    hipMemsetAsync(degi, 0, (size_t)n * 4, stream);
    deg_kernel<<<nb_edge, 256, 0, stream>>>(col, degi, E);
    block_sum_kernel<<<nb_scan, 512, 0, stream>>>(degi, bsums, n);
    scan_bsums_kernel<<<1, 256, 0, stream>>>(bsums, nb_scan);
    scan_write_kernel<<<nb_scan, 512, 0, stream>>>(degi, bsums, rowptr, n, E);
    dis_kernel<<<nb_node, 256, 0, stream>>>(degi, dis, n);
    hipMemsetAsync(degi, 0, (size_t)n * 4, stream);          // reuse as fill counters
    fill_csr_kernel<<<nb_edge, 256, 0, stream>>>(row, col, dis, rowptr, degi, csr, E);

    // ---- layer 1 ----
    gemm_tiled<128><<<nb_gemm, 256, 0, stream>>>(x, W1, xwB, n);
    gcn_pull_kernel<0><<<2048, 256, 0, stream>>>(xwB, csr, rowptr, dis, b1, B, n);

    // ---- layer 2 ----
    gemm_tiled<64><<<nb_gemm, 256, 0, stream>>>(B, W2, xwB, n);
    gcn_pull_kernel<1><<<2048, 256, 0, stream>>>(xwB, csr, rowptr, dis, b2, B, n);

    // ---- pool + classifier ----
    hipMemsetAsync(pool, 0, (64 * 64 + 64) * sizeof(float), stream);
    pool_kernel<<<(n + 1023) / 1024, 256, 0, stream>>>((const ushort*)B, batch, pool, cnt, n);
    final_kernel<<<1, 640, 0, stream>>>(pool, cnt, Wl, bl, out);
}

// Round 4
// 421.444 us; speedup vs baseline: 2.7708x; 1.1791x over previous
//
#include <hip/hip_runtime.h>

// ---------------------------------------------------------------------------
// GCN graph classifier — CSR pull aggregation + bf16 gather tables.
//   h1 = relu(gcnconv(x, W1, b1));  h2 = relu(gcnconv(h1, W2, b2));
//   g  = mean_pool(h2, batch);      out = g @ Wl + bl
// xw tables stored bf16 (halves random-gather traffic); accum always f32.
// ---------------------------------------------------------------------------

static __device__ inline ushort f32_to_bf16_rne(float f) {
    uint32_t u = __float_as_uint(f);
    uint32_t r = (u + 0x7fffu + ((u >> 16) & 1u)) >> 16;
    return (ushort)r;
}

// ---- degree histogram (int) ------------------------------------------------
__global__ __launch_bounds__(256) void deg_kernel(const int* __restrict__ col,
                                                  int* __restrict__ deg, int E) {
    int e = blockIdx.x * 256 + threadIdx.x;
    if (e < E) atomicAdd(&deg[col[e]], 1);
}

// ---- dis[i] = rsqrt(deg+1) -------------------------------------------------
__global__ __launch_bounds__(256) void dis_kernel(const int* __restrict__ deg,
                                                  float* __restrict__ dis, int n) {
    int i = blockIdx.x * 256 + threadIdx.x;
    if (i < n) dis[i] = rsqrtf((float)deg[i] + 1.0f);
}

// ---- scan step 1: per-block sums (512 elems/block) -------------------------
__global__ __launch_bounds__(512) void block_sum_kernel(const int* __restrict__ deg,
                                                        int* __restrict__ bsums, int n) {
    __shared__ int sm[512];
    int i = blockIdx.x * 512 + threadIdx.x;
    sm[threadIdx.x] = (i < n) ? deg[i] : 0;
    __syncthreads();
    for (int s = 256; s > 0; s >>= 1) {
        if (threadIdx.x < s) sm[threadIdx.x] += sm[threadIdx.x + s];
        __syncthreads();
    }
    if (threadIdx.x == 0) bsums[blockIdx.x] = sm[0];
}

// ---- scan step 2: exclusive scan of block sums (nb <= 256, one block) ------
__global__ __launch_bounds__(256) void scan_bsums_kernel(int* __restrict__ bsums, int nb) {
    __shared__ int sm[256];
    int v = (threadIdx.x < nb) ? bsums[threadIdx.x] : 0;
    sm[threadIdx.x] = v;
    __syncthreads();
    for (int off = 1; off < 256; off <<= 1) {
        int t = (threadIdx.x >= off) ? sm[threadIdx.x - off] : 0;
        __syncthreads();
        sm[threadIdx.x] += t;
        __syncthreads();
    }
    if (threadIdx.x < nb) bsums[threadIdx.x] = sm[threadIdx.x] - v;  // exclusive
}

// ---- scan step 3: local exclusive scan + block offset -> row_ptr -----------
__global__ __launch_bounds__(512) void scan_write_kernel(const int* __restrict__ deg,
                                                         const int* __restrict__ bsums,
                                                         int* __restrict__ rowptr,
                                                         int n, int E) {
    __shared__ int sm[512];
    int i = blockIdx.x * 512 + threadIdx.x;
    int v = (i < n) ? deg[i] : 0;
    sm[threadIdx.x] = v;
    __syncthreads();
    for (int off = 1; off < 512; off <<= 1) {
        int t = (threadIdx.x >= off) ? sm[threadIdx.x - off] : 0;
        __syncthreads();
        sm[threadIdx.x] += t;
        __syncthreads();
    }
    if (i < n) rowptr[i] = bsums[blockIdx.x] + sm[threadIdx.x] - v;  // exclusive
    if (blockIdx.x == 0 && threadIdx.x == 0) rowptr[n] = E;
}

// ---- CSR fill: csr[pos] = (src, norm) --------------------------------------
__global__ __launch_bounds__(256) void fill_csr_kernel(const int* __restrict__ row,
                                                       const int* __restrict__ col,
                                                       const float* __restrict__ dis,
                                                       const int* __restrict__ rowptr,
                                                       int* __restrict__ fill,
                                                       int2* __restrict__ csr, int E) {
    int e = blockIdx.x * 256 + threadIdx.x;
    if (e >= E) return;
    int r = row[e], c = col[e];
    int pos = rowptr[c] + atomicAdd(&fill[c], 1);
    csr[pos] = make_int2(r, __float_as_int(dis[r] * dis[c]));
}

// ---- register-tiled GEMM: out_bf16[n][64] = x[n][K] @ W[K][64] -------------
// 64-node x 64-out tile per block (256 thr), 4x4 per thread, K-chunks of 32.
template <int K>
__global__ __launch_bounds__(256) void gemm_tiled(const float* __restrict__ x,
                                                  const float* __restrict__ W,
                                                  ushort* __restrict__ out, int n) {
    __shared__ float As[32][64];     // [k][node]
    __shared__ float Ws[32 * 64];    // [k][out] flat
    const int tid = threadIdx.x;
    const int tr = tid >> 4;         // 0..15 -> node quad
    const int tc = tid & 15;         // 0..15 -> out quad
    const int base = blockIdx.x * 64;

    float acc[4][4];
#pragma unroll
    for (int i = 0; i < 4; ++i)
#pragma unroll
        for (int j = 0; j < 4; ++j) acc[i][j] = 0.0f;

    const int tnode = tid >> 3;          // 0..31
    const int tk4 = (tid & 7) * 4;       // 0,4,...,28

    for (int kc = 0; kc < K; kc += 32) {
        __syncthreads();
        // stage x[base..base+63][kc..kc+31] -> As[k][node]
#pragma unroll
        for (int h = 0; h < 2; ++h) {
            int m = tnode + h * 32;
            int node = base + m;
            float4 v = make_float4(0.f, 0.f, 0.f, 0.f);
            if (node < n) v = *(const float4*)&x[(size_t)node * K + kc + tk4];
            As[tk4 + 0][m] = v.x; As[tk4 + 1][m] = v.y;
            As[tk4 + 2][m] = v.z; As[tk4 + 3][m] = v.w;
        }
        // stage W[kc..kc+31][0..63] (contiguous 2048 floats)
#pragma unroll
        for (int r = 0; r < 2; ++r) {
            int o = tid * 4 + r * 1024;
            *(float4*)&Ws[o] = *(const float4*)&W[kc * 64 + o];
        }
        __syncthreads();
#pragma unroll
        for (int k = 0; k < 32; ++k) {
            float4 a = *(const float4*)&As[k][tr * 4];
            float4 b = *(const float4*)&Ws[k * 64 + tc * 4];
            const float av[4] = {a.x, a.y, a.z, a.w};
            const float bv[4] = {b.x, b.y, b.z, b.w};
#pragma unroll
            for (int i = 0; i < 4; ++i)
#pragma unroll
                for (int j = 0; j < 4; ++j)
                    acc[i][j] = fmaf(av[i], bv[j], acc[i][j]);
        }
    }
    // epilogue: bf16 store
#pragma unroll
    for (int i = 0; i < 4; ++i) {
        int node = base + tr * 4 + i;
        if (node < n) {
            ushort4 st;
            st.x = f32_to_bf16_rne(acc[i][0]);
            st.y = f32_to_bf16_rne(acc[i][1]);
            st.z = f32_to_bf16_rne(acc[i][2]);
            st.w = f32_to_bf16_rne(acc[i][3]);
            *(ushort4*)&out[(size_t)node * 64 + tc * 4] = st;
        }
    }
}

// ---- fused pull-aggregate + self-loop + bias + relu (bf16 gather) ----------
// wave per dst node; half-wave per edge; 4 edges per half in flight.
template <int OUT_BF16>
__global__ __launch_bounds__(256) void gcn_pull_kernel(const ushort* __restrict__ xw,
                                                       const int2* __restrict__ csr,
                                                       const int* __restrict__ rowptr,
                                                       const float* __restrict__ dis,
                                                       const float* __restrict__ b,
                                                       void* __restrict__ outv, int n) {
    const int lane = threadIdx.x & 63;
    const int wid = threadIdx.x >> 6;
    const int half = lane >> 5;          // 0/1 -> which edge of the pair
    const int q = lane & 31;             // feature pair index
    const float2 bb = ((const float2*)b)[q];

    for (int i = blockIdx.x * 4 + wid; i < n; i += gridDim.x * 4) {
        int s = rowptr[i], t = rowptr[i + 1];
        float ax = 0.0f, ay = 0.0f;
        if (half == 0) {                 // self loop counted once
            float di = dis[i];
            uint32_t u = *(const uint32_t*)(xw + ((size_t)i << 6) + (q << 1));
            float w = di * di;
            ax = w * __uint_as_float(u << 16);
            ay = w * __uint_as_float(u & 0xffff0000u);
        }
        int e = s + half;
        // 4 edges per half in flight (8 per wave)
        for (; e + 6 < t; e += 8) {
            int2 p0 = csr[e];
            int2 p1 = csr[e + 2];
            int2 p2 = csr[e + 4];
            int2 p3 = csr[e + 6];
            uint32_t u0 = *(const uint32_t*)(xw + ((size_t)p0.x << 6) + (q << 1));
            uint32_t u1 = *(const uint32_t*)(xw + ((size_t)p1.x << 6) + (q << 1));
            uint32_t u2 = *(const uint32_t*)(xw + ((size_t)p2.x << 6) + (q << 1));
            uint32_t u3 = *(const uint32_t*)(xw + ((size_t)p3.x << 6) + (q << 1));
            float n0 = __int_as_float(p0.y), n1 = __int_as_float(p1.y);
            float n2 = __int_as_float(p2.y), n3 = __int_as_float(p3.y);
            ax = fmaf(n0, __uint_as_float(u0 << 16), ax);
            ay = fmaf(n0, __uint_as_float(u0 & 0xffff0000u), ay);
            ax = fmaf(n1, __uint_as_float(u1 << 16), ax);
            ay = fmaf(n1, __uint_as_float(u1 & 0xffff0000u), ay);
            ax = fmaf(n2, __uint_as_float(u2 << 16), ax);
            ay = fmaf(n2, __uint_as_float(u2 & 0xffff0000u), ay);
            ax = fmaf(n3, __uint_as_float(u3 << 16), ax);
            ay = fmaf(n3, __uint_as_float(u3 & 0xffff0000u), ay);
        }
        for (; e < t; e += 2) {
            int2 p = csr[e];
            uint32_t u = *(const uint32_t*)(xw + ((size_t)p.x << 6) + (q << 1));
            float nr = __int_as_float(p.y);
            ax = fmaf(nr, __uint_as_float(u << 16), ax);
            ay = fmaf(nr, __uint_as_float(u & 0xffff0000u), ay);
        }
        // combine the two halves
        ax += __shfl_xor(ax, 32);
        ay += __shfl_xor(ay, 32);
        if (half == 0) {
            float v0 = fmaxf(ax + bb.x, 0.0f);
            float v1 = fmaxf(ay + bb.y, 0.0f);
            if (OUT_BF16) {
                ushort2 st = make_ushort2(f32_to_bf16_rne(v0), f32_to_bf16_rne(v1));
                *(ushort2*)((ushort*)outv + ((size_t)i << 6) + (q << 1)) = st;
            } else {
                *(float2*)((float*)outv + ((size_t)i << 6) + (q << 1)) = make_float2(v0, v1);
            }
        }
    }
}

// ---- segmented mean-pool (batch sorted, bf16 input): 32 nodes/wave ---------
__global__ __launch_bounds__(256) void pool_kernel(const ushort* __restrict__ h,
                                                   const int* __restrict__ batch,
                                                   float* __restrict__ pool,
                                                   float* __restrict__ cnt, int n) {
    const int lane = threadIdx.x & 63;
    const int wid = threadIdx.x >> 6;
    const int start = (blockIdx.x * 4 + wid) * 32;
    const int end = min(start + 32, n);
    if (start >= end) return;
    int gcur = batch[start];
    float acc = 0.0f;
    int c = 0;
    for (int i = start; i < end; ++i) {
        int g = batch[i];           // wave-uniform
        if (g != gcur) {
            atomicAdd(&pool[gcur * 64 + lane], acc);
            if (lane == 0) atomicAdd(&cnt[gcur], (float)c);
            acc = 0.0f; c = 0; gcur = g;
        }
        acc += __uint_as_float((uint32_t)h[(size_t)i * 64 + lane] << 16);
        ++c;
    }
    atomicAdd(&pool[gcur * 64 + lane], acc);
    if (lane == 0) atomicAdd(&cnt[gcur], (float)c);
}

// ---- final: out[64][10] = (pool/cnt) @ Wl + bl -----------------------------
__global__ __launch_bounds__(640) void final_kernel(const float* __restrict__ pool,
                                                    const float* __restrict__ cnt,
                                                    const float* __restrict__ Wl,
                                                    const float* __restrict__ bl,
                                                    float* __restrict__ out) {
    int tid = threadIdx.x;            // 640 = 64 graphs * 10 outputs
    int g = tid / 10, o = tid % 10;
    float inv = 1.0f / fmaxf(cnt[g], 1.0f);
    float acc = 0.0f;
#pragma unroll
    for (int l = 0; l < 64; ++l)
        acc = fmaf(pool[g * 64 + l] * inv, Wl[l * 10 + o], acc);
    out[tid] = acc + bl[o];
}

extern "C" void kernel_launch(void* const* d_in, const int* in_sizes, int n_in,
                              void* d_out, int out_size, void* d_ws, size_t ws_size,
                              hipStream_t stream) {
    const float* x  = (const float*)d_in[0];
    const float* W1 = (const float*)d_in[1];
    const float* b1 = (const float*)d_in[2];
    const float* W2 = (const float*)d_in[3];
    const float* b2 = (const float*)d_in[4];
    const float* Wl = (const float*)d_in[5];
    const float* bl = (const float*)d_in[6];
    const int*   ei = (const int*)d_in[7];    // [2, E] -> row = ei, col = ei + E
    const int*   batch = (const int*)d_in[8];
    float* out = (float*)d_out;

    const int n = in_sizes[8];           // 100000 nodes
    const int E = in_sizes[7] / 2;       // 1600000 edges
    const int F = 64;

    const int* row = ei;
    const int* col = ei + E;

    // ---- workspace layout (256B-aligned chunks) ----
    char* p = (char*)d_ws;
    auto alloc = [&](size_t bytes) {
        char* r = p;
        p += (bytes + 255) & ~(size_t)255;
        return r;
    };
    int*    degi   = (int*)   alloc((size_t)n * 4);          // deg, reused as fill
    int*    rowptr = (int*)   alloc((size_t)(n + 1) * 4);
    int*    bsums  = (int*)   alloc(256 * 4);
    float*  dis    = (float*) alloc((size_t)n * 4);
    int2*   csr    = (int2*)  alloc((size_t)E * 8);
    ushort* xwB    = (ushort*)alloc((size_t)n * F * 2);      // bf16 gather table
    float*  B      = (float*) alloc((size_t)n * F * 4);      // h1 f32 / h2 bf16 reuse
    float*  pool   = (float*) alloc(64 * 64 * 4);
    float*  cnt    = (float*) alloc(64 * 4);

    const int nb_edge = (E + 255) / 256;
    const int nb_node = (n + 255) / 256;
    const int nb_scan = (n + 511) / 512;     // 196 for n=100000
    const int nb_gemm = (n + 63) / 64;

    // ---- CSR build (shared by both layers) ----
    hipMemsetAsync(degi, 0, (size_t)n * 4, stream);
    deg_kernel<<<nb_edge, 256, 0, stream>>>(col, degi, E);
    block_sum_kernel<<<nb_scan, 512, 0, stream>>>(degi, bsums, n);
    scan_bsums_kernel<<<1, 256, 0, stream>>>(bsums, nb_scan);
    scan_write_kernel<<<nb_scan, 512, 0, stream>>>(degi, bsums, rowptr, n, E);
    dis_kernel<<<nb_node, 256, 0, stream>>>(degi, dis, n);
    hipMemsetAsync(degi, 0, (size_t)n * 4, stream);          // reuse as fill counters
    fill_csr_kernel<<<nb_edge, 256, 0, stream>>>(row, col, dis, rowptr, degi, csr, E);

    // ---- layer 1 ----
    gemm_tiled<128><<<nb_gemm, 256, 0, stream>>>(x, W1, xwB, n);
    gcn_pull_kernel<0><<<2048, 256, 0, stream>>>(xwB, csr, rowptr, dis, b1, B, n);

    // ---- layer 2 ----
    gemm_tiled<64><<<nb_gemm, 256, 0, stream>>>(B, W2, xwB, n);
    gcn_pull_kernel<1><<<2048, 256, 0, stream>>>(xwB, csr, rowptr, dis, b2, B, n);

    // ---- pool + classifier ----
    hipMemsetAsync(pool, 0, (64 * 64 + 64) * sizeof(float), stream);
    pool_kernel<<<(n + 127) / 128, 256, 0, stream>>>((const ushort*)B, batch, pool, cnt, n);
    final_kernel<<<1, 640, 0, stream>>>(pool, cnt, Wl, bl, out);
}